// Round 5
// baseline (740.946 us; speedup 1.0000x reference)
//
#include <hip/hip_runtime.h>

#define Tv 128

// ---- DPP / cross-lane helpers
template<int CTRL>
__device__ __forceinline__ float dppx(float x) {
  return __int_as_float(__builtin_amdgcn_update_dpp(0, __float_as_int(x), CTRL, 0xF, 0xF, true));
}
__device__ __forceinline__ float dpp_rm(float x, int ctrl, int rm) {
  switch (ctrl) {
    default: return 0.f;
    case 0x111: return __int_as_float(__builtin_amdgcn_update_dpp(0, __float_as_int(x), 0x111, 0xF, 0xF, true));
    case 0x112: return __int_as_float(__builtin_amdgcn_update_dpp(0, __float_as_int(x), 0x112, 0xF, 0xF, true));
    case 0x114: return __int_as_float(__builtin_amdgcn_update_dpp(0, __float_as_int(x), 0x114, 0xF, 0xF, true));
    case 0x118: return __int_as_float(__builtin_amdgcn_update_dpp(0, __float_as_int(x), 0x118, 0xF, 0xF, true));
    case 0x142: return __int_as_float(__builtin_amdgcn_update_dpp(0, __float_as_int(x), 0x142, 0xA, 0xF, true));
    case 0x143: return __int_as_float(__builtin_amdgcn_update_dpp(0, __float_as_int(x), 0x143, 0xC, 0xF, true));
  }
}
// full-wave64 sum, broadcast via readlane(63)
__device__ __forceinline__ float wave_sum(float x) {
  x += dpp_rm(x, 0x111, 0xF);
  x += dpp_rm(x, 0x112, 0xF);
  x += dpp_rm(x, 0x114, 0xF);
  x += dpp_rm(x, 0x118, 0xF);
  x += dpp_rm(x, 0x142, 0xA);
  x += dpp_rm(x, 0x143, 0xC);
  return __int_as_float(__builtin_amdgcn_readlane(__float_as_int(x), 63));
}
template<int M>
__device__ __forceinline__ float lane_xor(float x) {
  if constexpr (M == 1)       return dppx<0xB1>(x);    // quad_perm [1,0,3,2]
  else if constexpr (M == 2)  return dppx<0x4E>(x);    // quad_perm [2,3,0,1]
  else if constexpr (M == 8)  return dppx<0x128>(x);   // row_ror:8 == xor8
  else if constexpr (M == 32) return __shfl_xor(x, 32, 64);
  else return __int_as_float(__builtin_amdgcn_ds_swizzle(__float_as_int(x), (M << 10) | 0x1F));
}
__device__ __forceinline__ float bperm(int addr, float x) {
  return __int_as_float(__builtin_amdgcn_ds_bpermute(addr, __float_as_int(x)));
}
__device__ __forceinline__ float fast_rcp(float x){ return __builtin_amdgcn_rcpf(x); }
__device__ __forceinline__ float fast_rsq(float x){ return __builtin_amdgcn_rsqf(x); }
__device__ __forceinline__ float tanh_(float x){
  float e = __expf(2.0f * x);
  return 1.0f - 2.0f * fast_rcp(e + 1.0f);
}
__device__ __forceinline__ float sigm_(float x){
  return fast_rcp(1.0f + __expf(-x));
}

// State: 256 amps = 4 regs x 64 lanes. idx = reg(2b: bits 7..6) | L(6b: bits 5..0)
// qubit q <-> idx bit (7-q): q0,q1 -> reg bits 1,0; q2..q7 -> lane masks 32,16,8,4,2,1
template<int Q>
__device__ __forceinline__ void ry4(float* s, float cc, float ss, int L, int aX32) {
  if constexpr (Q == 0) {
    #pragma unroll
    for (int r = 0; r < 2; r++) {
      float a0 = s[r], a1 = s[r + 2];
      s[r]     = fmaf(cc, a0, -(ss * a1));
      s[r + 2] = fmaf(ss, a0,  (cc * a1));
    }
  } else if constexpr (Q == 1) {
    #pragma unroll
    for (int r = 0; r < 4; r += 2) {
      float a0 = s[r], a1 = s[r + 1];
      s[r]     = fmaf(cc, a0, -(ss * a1));
      s[r + 1] = fmaf(ss, a0,  (cc * a1));
    }
  } else if constexpr (Q == 2) {
    float ssn = (L & 32) ? ss : -ss;
    #pragma unroll
    for (int r = 0; r < 4; r++) {
      float o = bperm(aX32, s[r]);
      s[r] = fmaf(cc, s[r], ssn * o);
    }
  } else {
    constexpr int m = 16 >> (Q - 3);   // Q3->16, Q4->8, Q5->4, Q6->2, Q7->1
    float ssn = (L & m) ? ss : -ss;
    #pragma unroll
    for (int r = 0; r < 4; r++) {
      float o = lane_xor<m>(s[r]);
      s[r] = fmaf(cc, s[r], ssn * o);
    }
  }
}

struct __align__(16) SMem {
  float cs[4][66];    // per gate (cos,sin) at [(l*8+q)*2]
  float ipb[8][4];    // (ip_b, in_g, in_b, 0)
  float fbuf[16];     // encode factors (wave0 -> all)
  float zbuf[32];     // z[gate][qubit]
  float embp[2][2];   // emb-LN partials (waves 2,3)
  float projp[2][8];  // proj partials (waves 0,1)
  float outp[2][4];   // epilogue partials (waves 2,3)
  float ebuf[128];    // normalized e_t rows (W23 -> W01)
  float hbuf[128];    // h_t rows (W01 -> W23)
};

__global__ __launch_bounds__(256, 4) void qlstm_kernel(
    const float* __restrict__ x,     const float* __restrict__ pe,
    const float* __restrict__ emb_w, const float* __restrict__ emb_b,
    const float* __restrict__ emb_g, const float* __restrict__ emb_bt,
    const float* __restrict__ ip_w,  const float* __restrict__ ip_b,
    const float* __restrict__ in_g,  const float* __restrict__ in_b,
    const float* __restrict__ wq_i,  const float* __restrict__ wq_f,
    const float* __restrict__ wq_gt, const float* __restrict__ wq_o,
    const float* __restrict__ pi_w,  const float* __restrict__ pi_b,
    const float* __restrict__ pf_w,  const float* __restrict__ pf_b,
    const float* __restrict__ pg_w,  const float* __restrict__ pg_b,
    const float* __restrict__ po_w,  const float* __restrict__ po_b,
    const float* __restrict__ on_g,  const float* __restrict__ on_b,
    const float* __restrict__ out_w, const float* __restrict__ out_b,
    float* __restrict__ out)
{
  __shared__ SMem sm;
  const int tid = threadIdx.x;           // 0..255
  const int b   = blockIdx.x;
  const int w4  = tid >> 6;              // wave id 0..3 = VQC gate id
  const int L   = tid & 63;              // lane
  const int o8  = L & 7;
  const bool isW01 = (tid < 128);
  const int j   = tid & 127;             // row id (W01: rows; W23: same rows for emb/epilogue)

  // ---- stage (cos,sin) table (128 entries) + ipb
  if (tid < 128) {
    int gg = tid >> 5, rem = tid & 31;
    const float* wsel = (gg == 0) ? wq_i : (gg == 1) ? wq_f : (gg == 2) ? wq_gt : wq_o;
    float th = wsel[rem] * 0.5f;
    sm.cs[gg][rem * 2]     = __cosf(th);
    sm.cs[gg][rem * 2 + 1] = __sinf(th);
  }
  if (tid < 8) {
    sm.ipb[tid][0] = ip_b[tid];
    sm.ipb[tid][1] = in_g[tid];
    sm.ipb[tid][2] = in_b[tid];
    sm.ipb[tid][3] = 0.0f;
  }

  // ---- per-role persistent weights
  float ipw1[8], ipw2[8], gw[4][8], gb[4];     // W01
  float ew[8], ebb, egg, ebt, a_, bw_;         // W23 (a_=ong*ow, bw_=onb*ow)
  float h = 0.f, c = 0.f;                      // W01 recurrence
  float e_p = 0.f, e_c = 0.f, e_n;             // W23 e history
  float SW = 0.f, KB = 0.f;                    // W23 uniform epilogue consts

  if (isW01) {
    #pragma unroll
    for (int o = 0; o < 8; o++) {
      ipw1[o] = ip_w[o * 256 + j];
      ipw2[o] = ip_w[o * 256 + 128 + j];
    }
    #pragma unroll
    for (int gg = 0; gg < 4; gg++) {
      const float* pw = (gg == 0) ? pi_w : (gg == 1) ? pf_w : (gg == 2) ? pg_w : po_w;
      float4 a = *reinterpret_cast<const float4*>(pw + j * 8);
      float4 cq = *reinterpret_cast<const float4*>(pw + j * 8 + 4);
      gw[gg][0]=a.x; gw[gg][1]=a.y; gw[gg][2]=a.z; gw[gg][3]=a.w;
      gw[gg][4]=cq.x; gw[gg][5]=cq.y; gw[gg][6]=cq.z; gw[gg][7]=cq.w;
    }
    gb[0] = pi_b[j]; gb[1] = pf_b[j]; gb[2] = pg_b[j]; gb[3] = po_b[j];
  } else {
    float4 a = *reinterpret_cast<const float4*>(emb_w + j * 8);
    float4 cq = *reinterpret_cast<const float4*>(emb_w + j * 8 + 4);
    ew[0]=a.x; ew[1]=a.y; ew[2]=a.z; ew[3]=a.w; ew[4]=cq.x; ew[5]=cq.y; ew[6]=cq.z; ew[7]=cq.w;
    ebb = emb_b[j]; egg = emb_g[j]; ebt = emb_bt[j];
    float ow_ = out_w[j];
    a_  = on_g[j] * ow_;
    bw_ = on_b[j] * ow_;
  }

  // ---- lane-permutation addresses
  // composed CNOT (even pass c=0,2,4,6 then odd c=1,3,5): src idx = E(O(dest))
  int aA, aB, aX32;
  {
    int l1 = L ^ ((L & 16) >> 1) ^ ((L & 4) >> 1);
    int a0 = l1 ^ ((l1 & 32) >> 1) ^ ((l1 & 8) >> 1) ^ ((l1 & 2) >> 1);
    aA = a0 << 2;
    aB = (a0 ^ 48) << 2;
    aX32 = (L ^ 32) << 2;
  }
  const float* csg = sm.cs[w4];
  const float* xbase = x + (size_t)b * Tv * 8;
  const int wv = w4 - 2;   // W23 pair index 0/1

  // ---- priming: e_0 + SW/KB
  if (!isW01) {
    float4 a = *reinterpret_cast<const float4*>(xbase);
    float4 cq = *reinterpret_cast<const float4*>(xbase + 4);
    float xt[8] = {a.x,a.y,a.z,a.w,cq.x,cq.y,cq.z,cq.w};
    float er = ebb;
    #pragma unroll
    for (int k = 0; k < 8; k++) er = fmaf(xt[k], ew[k], er);
    e_n = er;  // raw, normalize after exchange
    float s1 = wave_sum(er), s2 = wave_sum(er * er);
    float r0 = wave_sum(a_), r1 = wave_sum(bw_);
    if (L == 0) {
      sm.embp[wv][0] = s1; sm.embp[wv][1] = s2;
      sm.outp[wv][0] = r0; sm.outp[wv][1] = r1;
    }
  }
  __syncthreads();
  if (!isW01) {
    float s1 = sm.embp[0][0] + sm.embp[1][0];
    float s2 = sm.embp[0][1] + sm.embp[1][1];
    float mn = s1 * 0.0078125f;
    float vr = fmaf(s2, 0.0078125f, -mn * mn);
    float inv = fast_rsq(vr + 1e-5f);
    e_c = (e_n - mn) * inv * egg + ebt + pe[j];
    sm.ebuf[j] = e_c;
    SW = sm.outp[0][0] + sm.outp[1][0];
    KB = sm.outp[0][1] + sm.outp[1][1] + out_b[0];
  }
  __syncthreads();

  #pragma unroll 1
  for (int t = 0; t < Tv; t++) {
    // ============ phase 1 ============
    float e01 = 0.f;
    if (isW01) {
      e01 = sm.ebuf[j];
      float p_[8];
      #pragma unroll
      for (int o = 0; o < 8; o++)
        p_[o] = fmaf(e01, ipw1[o], h * ipw2[o]);
      const int bb0 = L & 1, bb1 = L & 2, bb2 = L & 4;
      float q_[4];
      #pragma unroll
      for (int k = 0; k < 4; k++) {
        float keep = bb0 ? p_[2 * k + 1] : p_[2 * k];
        float send = bb0 ? p_[2 * k]     : p_[2 * k + 1];
        q_[k] = keep + lane_xor<1>(send);
      }
      float r_[2];
      #pragma unroll
      for (int k = 0; k < 2; k++) {
        float keep = bb1 ? q_[2 * k + 1] : q_[2 * k];
        float send = bb1 ? q_[2 * k]     : q_[2 * k + 1];
        r_[k] = keep + lane_xor<2>(send);
      }
      float u;
      {
        float keep = bb2 ? r_[1] : r_[0];
        float send = bb2 ? r_[0] : r_[1];
        u = keep + lane_xor<4>(send);
      }
      u += lane_xor<8>(u); u += lane_xor<16>(u); u += lane_xor<32>(u);
      if (L < 8) sm.projp[w4][L] = u;
    } else {
      // emb for t+1
      int tn = (t + 1) & (Tv - 1);
      float4 a = *reinterpret_cast<const float4*>(xbase + tn * 8);
      float4 cq = *reinterpret_cast<const float4*>(xbase + tn * 8 + 4);
      float xt[8] = {a.x,a.y,a.z,a.w,cq.x,cq.y,cq.z,cq.w};
      float er = ebb;
      #pragma unroll
      for (int k = 0; k < 8; k++) er = fmaf(xt[k], ew[k], er);
      e_n = er;
      float s1 = wave_sum(er), s2 = wave_sum(er * er);
      if (L == 0) { sm.embp[wv][0] = s1; sm.embp[wv][1] = s2; }
    }
    __syncthreads();                                   // ===== A

    // ============ phase 2 ============
    if (tid < 64) {
      // wave0: angles
      float u = sm.projp[0][o8] + sm.projp[1][o8];
      float4 ipbv = *reinterpret_cast<float4*>(&sm.ipb[o8][0]);
      float tv = tanh_(u + ipbv.x);
      float m1 = tv, m2 = tv * tv;
      m1 += lane_xor<1>(m1); m2 += lane_xor<1>(m2);
      m1 += lane_xor<2>(m1); m2 += lane_xor<2>(m2);
      m1 += lane_xor<4>(m1); m2 += lane_xor<4>(m2);
      float pm = m1 * 0.125f;
      float pv = fmaf(m2, 0.125f, -pm * pm);
      float theta = (tv - pm) * fast_rsq(pv + 1e-5f) * ipbv.y + ipbv.z;
      float ph = theta * 0.5f;
      float cE = __cosf(ph), sE = __sinf(ph);
      if (L < 8) { sm.fbuf[2 * L] = cE - sE; sm.fbuf[2 * L + 1] = cE + sE; }
    } else if (!isW01) {
      // normalize e_{t+1} -> ebuf
      {
        float s1 = sm.embp[0][0] + sm.embp[1][0];
        float s2 = sm.embp[0][1] + sm.embp[1][1];
        float mn = s1 * 0.0078125f;
        float vr = fmaf(s2, 0.0078125f, -mn * mn);
        float inv = fast_rsq(vr + 1e-5f);
        int tn = (t + 1) & (Tv - 1);
        e_n = (e_n - mn) * inv * egg + ebt + pe[tn * 128 + j];
        sm.ebuf[j] = e_n;
      }
      // epilogue partials for step t-1: y = h_{t-1} + e_{t-1}
      {
        float y = sm.hbuf[j] + e_p;
        float r0 = wave_sum(y), r1 = wave_sum(y * y), r2 = wave_sum(y * a_);
        if (L == 0) { sm.outp[wv][0] = r0; sm.outp[wv][1] = r1; sm.outp[wv][2] = r2; }
      }
    }
    __syncthreads();                                   // ===== B

    if (t && tid == 128) {
      float sy  = sm.outp[0][0] + sm.outp[1][0];
      float sy2 = sm.outp[0][1] + sm.outp[1][1];
      float sya = sm.outp[0][2] + sm.outp[1][2];
      float mn2 = sy * 0.0078125f;
      float vr2 = fmaf(sy2, 0.0078125f, -mn2 * mn2);
      float inv2 = fast_rsq(vr2 + 1e-5f);
      out[b * Tv + t - 1] = fmaf(inv2, sya - mn2 * SW, KB);
    }

    // ============ phase 3: VQC (all waves, one gate each) ============
    float f_[16];
    {
      float4 a0 = *reinterpret_cast<float4*>(&sm.fbuf[0]);
      float4 a1 = *reinterpret_cast<float4*>(&sm.fbuf[4]);
      float4 a2 = *reinterpret_cast<float4*>(&sm.fbuf[8]);
      float4 a3 = *reinterpret_cast<float4*>(&sm.fbuf[12]);
      f_[0]=a0.x; f_[1]=a0.y; f_[2]=a0.z; f_[3]=a0.w;
      f_[4]=a1.x; f_[5]=a1.y; f_[6]=a1.z; f_[7]=a1.w;
      f_[8]=a2.x; f_[9]=a2.y; f_[10]=a2.z; f_[11]=a2.w;
      f_[12]=a3.x; f_[13]=a3.y; f_[14]=a3.z; f_[15]=a3.w;
    }
    float s_[4];
    {
      float lf = f_[4 + ((L >> 5) & 1)] * f_[6 + ((L >> 4) & 1)]
               * f_[8 + ((L >> 3) & 1)] * f_[10 + ((L >> 2) & 1)]
               * f_[12 + ((L >> 1) & 1)] * f_[14 + (L & 1)];
      lf *= 0.0625f;
      s_[0] = lf * (f_[0] * f_[2]);
      s_[1] = lf * (f_[0] * f_[3]);
      s_[2] = lf * (f_[1] * f_[2]);
      s_[3] = lf * (f_[1] * f_[3]);
    }
    #pragma unroll
    for (int l = 0; l < 4; l++) {
      float t0 = bperm(aA, s_[0]);
      float t1 = bperm(aB, s_[1]);
      float t2 = bperm(aA, s_[3]);
      float t3 = bperm(aB, s_[2]);
      s_[0] = t0; s_[1] = t1; s_[2] = t2; s_[3] = t3;
      #define RYL(Q) { float2 cs2 = *reinterpret_cast<const float2*>(&csg[(l * 8 + Q) * 2]); \
                       ry4<Q>(s_, cs2.x, cs2.y, L, aX32); }
      RYL(0) RYL(1) RYL(2) RYL(3) RYL(4) RYL(5) RYL(6) RYL(7)
      #undef RYL
    }
    // measure
    {
      float p0 = s_[0]*s_[0], p1 = s_[1]*s_[1], p2v = s_[2]*s_[2], p3 = s_[3]*s_[3];
      float z0 = wave_sum((p0 + p1) - (p2v + p3));
      float z1 = wave_sum((p0 - p1) + (p2v - p3));
      float uS = p0 + p1 + p2v + p3;
      float v, d;
      v = bperm(aX32, uS); d = uS - v;
      float z2 = (L & 32) ? -d : d;
      z2 += lane_xor<16>(z2); z2 += lane_xor<8>(z2); z2 += lane_xor<4>(z2);
      z2 += lane_xor<2>(z2);  z2 += lane_xor<1>(z2);
      uS += v;
      v = lane_xor<16>(uS); d = uS - v;
      float z3 = (L & 16) ? -d : d;
      z3 += lane_xor<8>(z3); z3 += lane_xor<4>(z3); z3 += lane_xor<2>(z3); z3 += lane_xor<1>(z3);
      uS += v;
      v = lane_xor<8>(uS); d = uS - v;
      float z4 = (L & 8) ? -d : d;
      z4 += lane_xor<4>(z4); z4 += lane_xor<2>(z4); z4 += lane_xor<1>(z4);
      uS += v;
      v = lane_xor<4>(uS); d = uS - v;
      float z5 = (L & 4) ? -d : d;
      z5 += lane_xor<2>(z5); z5 += lane_xor<1>(z5);
      uS += v;
      v = lane_xor<2>(uS); d = uS - v;
      float z6 = (L & 2) ? -d : d;
      z6 += lane_xor<1>(z6);
      uS += v;
      v = lane_xor<1>(uS); d = uS - v;
      float z7 = (L & 1) ? -d : d;
      if (L < 8) {
        float zv = z0;
        zv = (L == 1) ? z1 : zv;
        zv = (L == 2) ? z2 : zv;
        zv = (L == 3) ? z3 : zv;
        zv = (L == 4) ? z4 : zv;
        zv = (L == 5) ? z5 : zv;
        zv = (L == 6) ? z6 : zv;
        zv = (L == 7) ? z7 : zv;
        sm.zbuf[w4 * 8 + L] = zv;
      }
    }
    __syncthreads();                                   // ===== C

    // ============ phase 4 ============
    if (isW01) {
      float acc[4];
      #pragma unroll
      for (int gg = 0; gg < 4; gg++) {
        float4 za0 = *reinterpret_cast<float4*>(&sm.zbuf[gg * 8]);
        float4 za1 = *reinterpret_cast<float4*>(&sm.zbuf[gg * 8 + 4]);
        float av = gb[gg];
        av = fmaf(za0.x, gw[gg][0], av); av = fmaf(za0.y, gw[gg][1], av);
        av = fmaf(za0.z, gw[gg][2], av); av = fmaf(za0.w, gw[gg][3], av);
        av = fmaf(za1.x, gw[gg][4], av); av = fmaf(za1.y, gw[gg][5], av);
        av = fmaf(za1.z, gw[gg][6], av); av = fmaf(za1.w, gw[gg][7], av);
        acc[gg] = av;
      }
      float it = sigm_(acc[0]), ft = sigm_(acc[1]), gt = tanh_(acc[2]), ot = sigm_(acc[3]);
      c = ft * c + it * gt;
      h = ot * tanh_(c);
      sm.hbuf[j] = h;
    } else {
      e_p = e_c;
      e_c = e_n;
    }
  }

  // ---- tail: epilogue for t = Tv-1
  __syncthreads();
  if (!isW01) {
    float y = sm.hbuf[j] + e_p;
    float r0 = wave_sum(y), r1 = wave_sum(y * y), r2 = wave_sum(y * a_);
    if (L == 0) { sm.outp[wv][0] = r0; sm.outp[wv][1] = r1; sm.outp[wv][2] = r2; }
  }
  __syncthreads();
  if (tid == 128) {
    float sy  = sm.outp[0][0] + sm.outp[1][0];
    float sy2 = sm.outp[0][1] + sm.outp[1][1];
    float sya = sm.outp[0][2] + sm.outp[1][2];
    float mn2 = sy * 0.0078125f;
    float vr2 = fmaf(sy2, 0.0078125f, -mn2 * mn2);
    float inv2 = fast_rsq(vr2 + 1e-5f);
    out[b * Tv + Tv - 1] = fmaf(inv2, sya - mn2 * SW, KB);
  }
}

extern "C" void kernel_launch(void* const* d_in, const int* in_sizes, int n_in,
                              void* d_out, int out_size, void* d_ws, size_t ws_size,
                              hipStream_t stream) {
  qlstm_kernel<<<dim3(1024), dim3(256), 0, stream>>>(
      (const float*)d_in[0],  (const float*)d_in[1],  (const float*)d_in[2],  (const float*)d_in[3],
      (const float*)d_in[4],  (const float*)d_in[5],  (const float*)d_in[6],  (const float*)d_in[7],
      (const float*)d_in[8],  (const float*)d_in[9],  (const float*)d_in[10], (const float*)d_in[11],
      (const float*)d_in[12], (const float*)d_in[13], (const float*)d_in[14], (const float*)d_in[15],
      (const float*)d_in[16], (const float*)d_in[17], (const float*)d_in[18], (const float*)d_in[19],
      (const float*)d_in[20], (const float*)d_in[21], (const float*)d_in[22], (const float*)d_in[23],
      (const float*)d_in[24], (const float*)d_in[25],
      (float*)d_out);
}

// Round 6
// 658.041 us; speedup vs baseline: 1.1260x; 1.1260x over previous
//
#include <hip/hip_runtime.h>

#define Tv 128

typedef float v2 __attribute__((ext_vector_type(2)));

__device__ __forceinline__ v2 pkfma(v2 a, v2 b, v2 c) {
  return __builtin_elementwise_fma(a, b, c);
}

// ---- DPP / cross-lane helpers
template<int CTRL>
__device__ __forceinline__ float dppx(float x) {
  return __int_as_float(__builtin_amdgcn_update_dpp(0, __float_as_int(x), CTRL, 0xF, 0xF, true));
}
__device__ __forceinline__ float dpp_rm(float x, int ctrl, int rm) {
  switch (ctrl) {
    default: return 0.f;
    case 0x111: return __int_as_float(__builtin_amdgcn_update_dpp(0, __float_as_int(x), 0x111, 0xF, 0xF, true));
    case 0x112: return __int_as_float(__builtin_amdgcn_update_dpp(0, __float_as_int(x), 0x112, 0xF, 0xF, true));
    case 0x114: return __int_as_float(__builtin_amdgcn_update_dpp(0, __float_as_int(x), 0x114, 0xF, 0xF, true));
    case 0x118: return __int_as_float(__builtin_amdgcn_update_dpp(0, __float_as_int(x), 0x118, 0xF, 0xF, true));
    case 0x142: return __int_as_float(__builtin_amdgcn_update_dpp(0, __float_as_int(x), 0x142, 0xA, 0xF, true));
    case 0x143: return __int_as_float(__builtin_amdgcn_update_dpp(0, __float_as_int(x), 0x143, 0xC, 0xF, true));
  }
}
// full-wave64 sum, broadcast via readlane(63)
__device__ __forceinline__ float wave_sum(float x) {
  x += dpp_rm(x, 0x111, 0xF);
  x += dpp_rm(x, 0x112, 0xF);
  x += dpp_rm(x, 0x114, 0xF);
  x += dpp_rm(x, 0x118, 0xF);
  x += dpp_rm(x, 0x142, 0xA);
  x += dpp_rm(x, 0x143, 0xC);
  return __int_as_float(__builtin_amdgcn_readlane(__float_as_int(x), 63));
}
template<int M>
__device__ __forceinline__ float lane_xor(float x) {
  if constexpr (M == 1)       return dppx<0xB1>(x);    // quad_perm [1,0,3,2]
  else if constexpr (M == 2)  return dppx<0x4E>(x);    // quad_perm [2,3,0,1]
  else if constexpr (M == 8)  return dppx<0x128>(x);   // row_ror:8 == xor8
  else if constexpr (M == 32) return __shfl_xor(x, 32, 64);
  else return __int_as_float(__builtin_amdgcn_ds_swizzle(__float_as_int(x), (M << 10) | 0x1F));
}
__device__ __forceinline__ float bperm(int addr, float x) {
  return __int_as_float(__builtin_amdgcn_ds_bpermute(addr, __float_as_int(x)));
}
__device__ __forceinline__ float rdlane(float x, int l) {
  return __int_as_float(__builtin_amdgcn_readlane(__float_as_int(x), l));
}
__device__ __forceinline__ float fast_rcp(float x){ return __builtin_amdgcn_rcpf(x); }
__device__ __forceinline__ float fast_rsq(float x){ return __builtin_amdgcn_rsqf(x); }
__device__ __forceinline__ float tanh_(float x){
  float e = __expf(2.0f * x);
  return 1.0f - 2.0f * fast_rcp(e + 1.0f);
}
__device__ __forceinline__ float sigm_(float x){
  return fast_rcp(1.0f + __expf(-x));
}

// State: 256 amps = 8 regs x 32 lanes, packed as v2 S[4]; s[r] = S[r>>1][r&1].
// idx = reg(3b: bits 7..5) | l5(5b: bits 4..0).
// q0 -> reg bit2 (S[k]<->S[k+2]); q1 -> reg bit1 (S[k]<->S[k+1]); q2 -> reg bit0 (x<->y);
// q3..q7 -> lane masks 16,8,4,2,1.
template<int Q>
__device__ __forceinline__ void ry_pk(v2* S, float cc, float ss, int l5) {
  const v2 cc2 = {cc, cc};
  if constexpr (Q == 0) {
    const v2 ss2 = {ss, ss};
    #pragma unroll
    for (int k = 0; k < 2; k++) {
      v2 a0 = S[k], a1 = S[k + 2];
      S[k]     = pkfma(cc2, a0, -(ss2 * a1));
      S[k + 2] = pkfma(ss2, a0,  (cc2 * a1));
    }
  } else if constexpr (Q == 1) {
    const v2 ss2 = {ss, ss};
    #pragma unroll
    for (int k = 0; k < 4; k += 2) {
      v2 a0 = S[k], a1 = S[k + 1];
      S[k]     = pkfma(cc2, a0, -(ss2 * a1));
      S[k + 1] = pkfma(ss2, a0,  (cc2 * a1));
    }
  } else if constexpr (Q == 2) {
    const v2 nss = {-ss, ss};
    #pragma unroll
    for (int k = 0; k < 4; k++) {
      v2 a = S[k];
      v2 sw = __builtin_shufflevector(a, a, 1, 0);
      S[k] = pkfma(cc2, a, nss * sw);
    }
  } else {
    constexpr int m = 16 >> (Q - 3);
    float ssn = (l5 & m) ? ss : -ss;
    const v2 ssn2 = {ssn, ssn};
    #pragma unroll
    for (int k = 0; k < 4; k++) {
      v2 o;
      o.x = lane_xor<m>(S[k].x);
      o.y = lane_xor<m>(S[k].y);
      S[k] = pkfma(cc2, S[k], ssn2 * o);
    }
  }
}

struct __align__(16) SMem {
  float cs[4][66];    // per gate: (cos,sin) at [(l*8+q)*2]
  float ipb[8][4];    // (ip_b, in_g, in_b, 0)
  float zbuf[32];     // z[gate][qubit]
  float embp[2][2];   // emb-LN partials (s1,s2)
  float projp[2][8];  // proj partials
  float outp[2][4];   // out-epilogue partials (init: SW/KB)
};

__global__ __launch_bounds__(128, 2) void qlstm_kernel(
    const float* __restrict__ x,     const float* __restrict__ pe,
    const float* __restrict__ emb_w, const float* __restrict__ emb_b,
    const float* __restrict__ emb_g, const float* __restrict__ emb_bt,
    const float* __restrict__ ip_w,  const float* __restrict__ ip_b,
    const float* __restrict__ in_g,  const float* __restrict__ in_b,
    const float* __restrict__ wq_i,  const float* __restrict__ wq_f,
    const float* __restrict__ wq_gt, const float* __restrict__ wq_o,
    const float* __restrict__ pi_w,  const float* __restrict__ pi_b,
    const float* __restrict__ pf_w,  const float* __restrict__ pf_b,
    const float* __restrict__ pg_w,  const float* __restrict__ pg_b,
    const float* __restrict__ po_w,  const float* __restrict__ po_b,
    const float* __restrict__ on_g,  const float* __restrict__ on_b,
    const float* __restrict__ out_w, const float* __restrict__ out_b,
    float* __restrict__ out)
{
  __shared__ SMem sm;
  const int tid = threadIdx.x;          // 0..127 = row j
  const int b   = blockIdx.x;
  const int w   = tid >> 6;             // wave 0/1
  const int L   = tid & 63;
  const int l5  = L & 31;
  const int gate = w * 2 + (L >> 5);    // 0..3 = i,f,g,o
  const int o8  = L & 7;

  // ---- stage (cos,sin) table
  {
    int gg = tid >> 5, rem = tid & 31;
    const float* wsel = (gg == 0) ? wq_i : (gg == 1) ? wq_f : (gg == 2) ? wq_gt : wq_o;
    float th = wsel[rem] * 0.5f;
    sm.cs[gg][rem * 2]     = __cosf(th);
    sm.cs[gg][rem * 2 + 1] = __sinf(th);
  }
  if (tid < 8) {
    sm.ipb[tid][0] = ip_b[tid];
    sm.ipb[tid][1] = in_g[tid];
    sm.ipb[tid][2] = in_b[tid];
    sm.ipb[tid][3] = 0.0f;
  }

  // ---- persistent per-thread weights (row j = tid)
  const int j = tid;
  v2 EW[4];
  {
    float4 a = *reinterpret_cast<const float4*>(emb_w + j * 8);
    float4 c = *reinterpret_cast<const float4*>(emb_w + j * 8 + 4);
    EW[0] = {a.x, a.y}; EW[1] = {a.z, a.w}; EW[2] = {c.x, c.y}; EW[3] = {c.z, c.w};
  }
  float ebb = emb_b[j], egg = emb_g[j], ebt = emb_bt[j];
  v2 IPW1[4], IPW2[4];
  #pragma unroll
  for (int k = 0; k < 4; k++) {
    IPW1[k] = {ip_w[(2 * k) * 256 + j],       ip_w[(2 * k + 1) * 256 + j]};
    IPW2[k] = {ip_w[(2 * k) * 256 + 128 + j], ip_w[(2 * k + 1) * 256 + 128 + j]};
  }
  v2 GW[4][4];
  #pragma unroll
  for (int gg = 0; gg < 4; gg++) {
    const float* pw = (gg == 0) ? pi_w : (gg == 1) ? pf_w : (gg == 2) ? pg_w : po_w;
    float4 a = *reinterpret_cast<const float4*>(pw + j * 8);
    float4 c = *reinterpret_cast<const float4*>(pw + j * 8 + 4);
    GW[gg][0] = {a.x, a.y}; GW[gg][1] = {a.z, a.w};
    GW[gg][2] = {c.x, c.y}; GW[gg][3] = {c.z, c.w};
  }
  float gb[4] = {pi_b[j], pf_b[j], pg_b[j], po_b[j]};
  float ong = on_g[j], onb = on_b[j], ow_ = out_w[j];
  float outb = out_b[0];
  float a_ = ong * ow_;

  // Composed per-layer CNOT permutation (verified R4)
  const int grp = L & 32;
  int aC0, aC1;
  {
    int l1 = l5 ^ ((l5 & 16) >> 1) ^ ((l5 & 4) >> 1);
    int lb = l1 ^ ((l1 & 8) >> 1) ^ ((l1 & 2) >> 1);
    aC0 = (grp | lb) << 2;
    aC1 = (grp | (lb ^ 16)) << 2;
  }

  const float* csg = sm.cs[gate];
  float h = 0.f, c = 0.f;
  const float* xbase = x + (size_t)b * Tv * 8;

  // ---- pre-loop: e_0 + SW/KB partials, single barrier
  float e;
  {
    float4 a = *reinterpret_cast<const float4*>(xbase);
    float4 cq = *reinterpret_cast<const float4*>(xbase + 4);
    v2 XT[4] = {{a.x,a.y},{a.z,a.w},{cq.x,cq.y},{cq.z,cq.w}};
    v2 acc = XT[0] * EW[0];
    acc = pkfma(XT[1], EW[1], acc);
    acc = pkfma(XT[2], EW[2], acc);
    acc = pkfma(XT[3], EW[3], acc);
    float er = ebb + acc.x + acc.y;
    float s1 = wave_sum(er), s2 = wave_sum(er * er);
    float r0 = wave_sum(a_), r1 = wave_sum(onb * ow_);
    if (L == 0) {
      sm.embp[w][0] = s1; sm.embp[w][1] = s2;
      sm.outp[w][0] = r0; sm.outp[w][1] = r1;
    }
    __syncthreads();
    s1 = sm.embp[0][0] + sm.embp[1][0];
    s2 = sm.embp[0][1] + sm.embp[1][1];
    float mn = s1 * 0.0078125f;
    float vr = fmaf(s2, 0.0078125f, -mn * mn);
    float inv = fast_rsq(vr + 1e-5f);
    e = (er - mn) * inv * egg + ebt + pe[j];
  }
  const float SW = sm.outp[0][0] + sm.outp[1][0];
  const float KB = sm.outp[0][1] + sm.outp[1][1] + outb;

  #pragma unroll 1
  for (int t = 0; t < Tv; t++) {
    // ---- prefetch next x,pe
    v2 XN[4]; float pen;
    {
      int tn = (t + 1) & (Tv - 1);
      float4 a = *reinterpret_cast<const float4*>(xbase + tn * 8);
      float4 cq = *reinterpret_cast<const float4*>(xbase + tn * 8 + 4);
      XN[0] = {a.x,a.y}; XN[1] = {a.z,a.w}; XN[2] = {cq.x,cq.y}; XN[3] = {cq.z,cq.w};
      pen = pe[tn * 128 + j];
    }

    // ---- proj: p_o = e*ipw1[o] + h*ipw2[o] (packed), butterfly transpose-reduce
    const v2 e2 = {e, e}, h2 = {h, h};
    v2 P2[4];
    #pragma unroll
    for (int k = 0; k < 4; k++)
      P2[k] = pkfma(e2, IPW1[k], h2 * IPW2[k]);
    const int bb0 = L & 1, bb1 = L & 2, bb2 = L & 4;
    float q_[4];
    #pragma unroll
    for (int k = 0; k < 4; k++) {
      float keep = bb0 ? P2[k].y : P2[k].x;
      float send = bb0 ? P2[k].x : P2[k].y;
      q_[k] = keep + lane_xor<1>(send);
    }
    float r_[2];
    #pragma unroll
    for (int k = 0; k < 2; k++) {
      float keep = bb1 ? q_[2 * k + 1] : q_[2 * k];
      float send = bb1 ? q_[2 * k]     : q_[2 * k + 1];
      r_[k] = keep + lane_xor<2>(send);
    }
    float u;
    {
      float keep = bb2 ? r_[1] : r_[0];
      float send = bb2 ? r_[0] : r_[1];
      u = keep + lane_xor<4>(send);
    }
    u += lane_xor<8>(u); u += lane_xor<16>(u); u += lane_xor<32>(u);
    if (L < 8) sm.projp[w][L] = u;
    __syncthreads();                                  // ===== barrier 1
    u += sm.projp[1 - w][o8];
    if (t && tid == 0) {                              // emit out[t-1] (pipelined)
      float sy  = sm.outp[0][0] + sm.outp[1][0];
      float sy2 = sm.outp[0][1] + sm.outp[1][1];
      float sya = sm.outp[0][2] + sm.outp[1][2];
      float mn2 = sy * 0.0078125f;
      float vr2 = fmaf(sy2, 0.0078125f, -mn2 * mn2);
      float inv2 = fast_rsq(vr2 + 1e-5f);
      out[b * Tv + t - 1] = fmaf(inv2, sya - mn2 * SW, KB);
    }

    // ---- angles: tanh + LN(8) -> encode factors, broadcast via readlane
    float4 ipbv = *reinterpret_cast<float4*>(&sm.ipb[o8][0]);
    float tv = tanh_(u + ipbv.x);
    float m1 = tv, m2 = tv * tv;
    m1 += lane_xor<1>(m1); m2 += lane_xor<1>(m2);
    m1 += lane_xor<2>(m1); m2 += lane_xor<2>(m2);
    m1 += lane_xor<4>(m1); m2 += lane_xor<4>(m2);
    float pm = m1 * 0.125f;
    float pv = fmaf(m2, 0.125f, -pm * pm);
    float theta = (tv - pm) * fast_rsq(pv + 1e-5f) * ipbv.y + ipbv.z;
    float ph = theta * 0.5f;
    float cE = __cosf(ph), sE = __sinf(ph);
    float fm = cE - sE, fp = cE + sE;
    float f_[16];
    #pragma unroll
    for (int qq = 0; qq < 8; qq++) {
      f_[2 * qq]     = rdlane(fm, qq);
      f_[2 * qq + 1] = rdlane(fp, qq);
    }

    // ---- VQC encode (packed)
    v2 S[4];
    {
      float g01_[4];
      #pragma unroll
      for (int i = 0; i < 4; i++)
        g01_[i] = f_[(i >> 1) & 1] * f_[2 + (i & 1)];
      float lf = f_[6 + ((l5 >> 4) & 1)] * f_[8 + ((l5 >> 3) & 1)]
               * f_[10 + ((l5 >> 2) & 1)] * f_[12 + ((l5 >> 1) & 1)]
               * f_[14 + (l5 & 1)];
      lf *= 0.0625f;
      const v2 F45 = {f_[4], f_[5]};
      #pragma unroll
      for (int k = 0; k < 4; k++) {
        float tk = lf * g01_[k];
        v2 tk2 = {tk, tk};
        S[k] = tk2 * F45;
      }
    }

    // ---- 4 variational layers: one composed bpermute + 8 packed RYs each
    #pragma unroll
    for (int l = 0; l < 4; l++) {
      v2 N0, N1, N2, N3;
      N0.x = bperm(aC0, S[0].x); N0.y = bperm(aC1, S[0].y);
      N1.x = bperm(aC1, S[1].y); N1.y = bperm(aC0, S[1].x);
      N2.x = bperm(aC0, S[3].x); N2.y = bperm(aC1, S[3].y);
      N3.x = bperm(aC1, S[2].y); N3.y = bperm(aC0, S[2].x);
      S[0] = N0; S[1] = N1; S[2] = N2; S[3] = N3;
      #define RYL(Q) { float2 cs2 = *reinterpret_cast<const float2*>(&csg[(l * 8 + Q) * 2]); \
                       ry_pk<Q>(S, cs2.x, cs2.y, l5); }
      RYL(0) RYL(1) RYL(2) RYL(3) RYL(4) RYL(5) RYL(6) RYL(7)
      #undef RYL
    }

    // ---- measure z_q (packed partials, scalar trees)
    v2 P[4];
    #pragma unroll
    for (int k = 0; k < 4; k++) P[k] = S[k] * S[k];
    v2 A = P[0] + P[2];          // {aa0, aa1}
    v2 B = P[1] + P[3];          // {aa2, aa3}
    v2 D = (P[0] - P[2]) + (P[1] - P[3]);
    float z0 = D.x + D.y;
    v2 Ev = A - B;
    float z1 = Ev.x + Ev.y;
    v2 G = A + B;
    float z2 = G.x - G.y;
    float S_ = G.x + G.y;
    z0 += lane_xor<1>(z0); z1 += lane_xor<1>(z1); z2 += lane_xor<1>(z2);
    z0 += lane_xor<2>(z0); z1 += lane_xor<2>(z1); z2 += lane_xor<2>(z2);
    z0 += lane_xor<4>(z0); z1 += lane_xor<4>(z1); z2 += lane_xor<4>(z2);
    z0 += lane_xor<8>(z0); z1 += lane_xor<8>(z1); z2 += lane_xor<8>(z2);
    z0 += lane_xor<16>(z0); z1 += lane_xor<16>(z1); z2 += lane_xor<16>(z2);
    float v, d, uS;
    v = lane_xor<16>(S_); d = S_ - v; uS = S_ + v;
    float z3 = (l5 & 16) ? -d : d;
    z3 += lane_xor<8>(z3); z3 += lane_xor<4>(z3); z3 += lane_xor<2>(z3); z3 += lane_xor<1>(z3);
    v = lane_xor<8>(uS); d = uS - v; uS = uS + v;
    float z4 = (l5 & 8) ? -d : d;
    z4 += lane_xor<4>(z4); z4 += lane_xor<2>(z4); z4 += lane_xor<1>(z4);
    v = lane_xor<4>(uS); d = uS - v; uS = uS + v;
    float z5 = (l5 & 4) ? -d : d;
    z5 += lane_xor<2>(z5); z5 += lane_xor<1>(z5);
    v = lane_xor<2>(uS); d = uS - v; uS = uS + v;
    float z6 = (l5 & 2) ? -d : d;
    z6 += lane_xor<1>(z6);
    v = lane_xor<1>(uS); d = uS - v;
    float z7 = (l5 & 1) ? -d : d;

    if (l5 < 8) {
      float zv = z0;
      zv = (l5 == 1) ? z1 : zv;
      zv = (l5 == 2) ? z2 : zv;
      zv = (l5 == 3) ? z3 : zv;
      zv = (l5 == 4) ? z4 : zv;
      zv = (l5 == 5) ? z5 : zv;
      zv = (l5 == 6) ? z6 : zv;
      zv = (l5 == 7) ? z7 : zv;
      sm.zbuf[gate * 8 + l5] = zv;
    }

    // ---- next-step emb partials (recurrence-independent; rides barrier 2)
    v2 acc = XN[0] * EW[0];
    acc = pkfma(XN[1], EW[1], acc);
    acc = pkfma(XN[2], EW[2], acc);
    acc = pkfma(XN[3], EW[3], acc);
    float en_raw = ebb + acc.x + acc.y;
    {
      float s1n = wave_sum(en_raw), s2n = wave_sum(en_raw * en_raw);
      if (L == 0) { sm.embp[w][0] = s1n; sm.embp[w][1] = s2n; }
    }
    __syncthreads();                                  // ===== barrier 2

    // ---- gate projections + LSTM cell (packed dot products)
    float acg[4];
    #pragma unroll
    for (int gg = 0; gg < 4; gg++) {
      float4 za0 = *reinterpret_cast<float4*>(&sm.zbuf[gg * 8]);
      float4 za1 = *reinterpret_cast<float4*>(&sm.zbuf[gg * 8 + 4]);
      v2 Z0 = {za0.x, za0.y}, Z1 = {za0.z, za0.w};
      v2 Z2 = {za1.x, za1.y}, Z3 = {za1.z, za1.w};
      v2 av = Z0 * GW[gg][0];
      av = pkfma(Z1, GW[gg][1], av);
      av = pkfma(Z2, GW[gg][2], av);
      av = pkfma(Z3, GW[gg][3], av);
      acg[gg] = gb[gg] + av.x + av.y;
    }
    float it = sigm_(acg[0]), ft = sigm_(acg[1]), gt = tanh_(acg[2]), ot = sigm_(acg[3]);
    c = ft * c + it * gt;
    h = ot * tanh_(c);

    // ---- normalize e_{t+1}
    float en;
    {
      float s1 = sm.embp[0][0] + sm.embp[1][0];
      float s2 = sm.embp[0][1] + sm.embp[1][1];
      float mn = s1 * 0.0078125f;
      float vr = fmaf(s2, 0.0078125f, -mn * mn);
      float inv = fast_rsq(vr + 1e-5f);
      en = (en_raw - mn) * inv * egg + ebt + pen;
    }

    // ---- epilogue partials for step t (consumed at next barrier 1)
    {
      float y = h + e;
      float ry0 = wave_sum(y), ry1 = wave_sum(y * y), ry2 = wave_sum(y * a_);
      if (L == 0) { sm.outp[w][0] = ry0; sm.outp[w][1] = ry1; sm.outp[w][2] = ry2; }
    }
    e = en;
  }

  __syncthreads();
  if (tid == 0) {
    float sy  = sm.outp[0][0] + sm.outp[1][0];
    float sy2 = sm.outp[0][1] + sm.outp[1][1];
    float sya = sm.outp[0][2] + sm.outp[1][2];
    float mn2 = sy * 0.0078125f;
    float vr2 = fmaf(sy2, 0.0078125f, -mn2 * mn2);
    float inv2 = fast_rsq(vr2 + 1e-5f);
    out[b * Tv + Tv - 1] = fmaf(inv2, sya - mn2 * SW, KB);
  }
}

extern "C" void kernel_launch(void* const* d_in, const int* in_sizes, int n_in,
                              void* d_out, int out_size, void* d_ws, size_t ws_size,
                              hipStream_t stream) {
  qlstm_kernel<<<dim3(1024), dim3(128), 0, stream>>>(
      (const float*)d_in[0],  (const float*)d_in[1],  (const float*)d_in[2],  (const float*)d_in[3],
      (const float*)d_in[4],  (const float*)d_in[5],  (const float*)d_in[6],  (const float*)d_in[7],
      (const float*)d_in[8],  (const float*)d_in[9],  (const float*)d_in[10], (const float*)d_in[11],
      (const float*)d_in[12], (const float*)d_in[13], (const float*)d_in[14], (const float*)d_in[15],
      (const float*)d_in[16], (const float*)d_in[17], (const float*)d_in[18], (const float*)d_in[19],
      (const float*)d_in[20], (const float*)d_in[21], (const float*)d_in[22], (const float*)d_in[23],
      (const float*)d_in[24], (const float*)d_in[25],
      (float*)d_out);
}